// Round 1
// baseline (304.389 us; speedup 1.0000x reference)
//
#include <hip/hip_runtime.h>

// TV-gradient divergence, fused single pass.
// d = ddH(u0) + ddW(u1), u = grad(x)/sqrt(1+|grad(x)|^2), jnp.gradient semantics
// (central diff interior, first-order one-sided at boundaries).
// Boundary handling: one-sided diff == central diff vs. a linearly extrapolated
// ghost value (g(-1) = 2 g(0) - g(1)), applied to x for the inner gradient and
// to u0/u1 (via LDS fixup) for the outer gradient.

constexpr int H  = 1024;
constexpr int W  = 1024;
constexpr int TH = 32;            // output tile rows
constexpr int TW = 64;            // output tile cols

constexpr int XS_R = TH + 4;      // 36 rows: image rows ti0-2 .. ti0+TH+1
constexpr int XS_C = TW + 8;      // 72 cols: image cols tj0-4 .. tj0+TW+3 (16B-aligned f4 loads; halo 2 used)
constexpr int U0_R = TH + 2;      // 34: image rows ti0-1 .. ti0+TH
constexpr int U0_C = TW;          // 64: image cols tj0 .. tj0+TW-1
constexpr int U0_S = TW + 1;      // 65 stride (bank-conflict pad)
constexpr int U1_R = TH;          // 32: image rows ti0 .. ti0+TH-1
constexpr int U1_C = TW + 2;      // 66: image cols tj0-1 .. tj0+TW
constexpr int U1_S = TW + 3;      // 67 stride (bank-conflict pad)

__device__ __forceinline__ float x_ext(const float* __restrict__ Xs, int r, int c) {
  // Load with one-step linear extrapolation outside the image. Cells 2 steps
  // outside (corners / row -2 etc.) are only consumed by u-values that get
  // overwritten by the u-fixup, so any finite value is fine there.
  if (r < 0) {
    int cc = c < 0 ? 0 : (c >= W ? W - 1 : c);
    return 2.0f * Xs[cc] - Xs[W + cc];
  }
  if (r >= H) {
    int cc = c < 0 ? 0 : (c >= W ? W - 1 : c);
    return 2.0f * Xs[(size_t)(H - 1) * W + cc] - Xs[(size_t)(H - 2) * W + cc];
  }
  if (c < 0)  return 2.0f * Xs[(size_t)r * W]           - Xs[(size_t)r * W + 1];
  if (c >= W) return 2.0f * Xs[(size_t)r * W + (W - 1)] - Xs[(size_t)r * W + (W - 2)];
  return Xs[(size_t)r * W + c];
}

__global__ __launch_bounds__(256) void tv_grad_kernel(const float* __restrict__ X,
                                                      float* __restrict__ D) {
  __shared__ float xs [XS_R][XS_C];
  __shared__ float u0s[U0_R][U0_S];
  __shared__ float u1s[U1_R][U1_S];

  const int tj0 = blockIdx.x * TW;
  const int ti0 = blockIdx.y * TH;
  const size_t soff = (size_t)blockIdx.z * H * W;
  const float* Xs = X + soff;
  float*       Ds = D + soff;
  const int tid = threadIdx.x;

  // ---- stage x tile (+halo) into LDS --------------------------------------
  const bool interior = (ti0 >= 2) && (ti0 + TH + 2 <= H) &&
                        (tj0 >= 4) && (tj0 + TW + 4 <= W);
  if (interior) {
    const float* base = Xs + (size_t)(ti0 - 2) * W + (tj0 - 4);
    // 36 rows x 18 float4 = 648 vector loads, 16B aligned (tj0-4 ≡ 0 mod 4)
    for (int idx = tid; idx < XS_R * (XS_C / 4); idx += 256) {
      int r  = idx / (XS_C / 4);
      int c4 = idx - r * (XS_C / 4);
      float4 v = *reinterpret_cast<const float4*>(base + (size_t)r * W + 4 * c4);
      *reinterpret_cast<float4*>(&xs[r][4 * c4]) = v;
    }
  } else {
    for (int idx = tid; idx < XS_R * XS_C; idx += 256) {
      int r = idx / XS_C;
      int c = idx - r * XS_C;
      xs[r][c] = x_ext(Xs, ti0 - 2 + r, tj0 - 4 + c);
    }
  }
  __syncthreads();

  // ---- u0 = gx/norm on (34 x 64): rows ti0-1..ti0+TH, cols tj0..tj0+TW-1 --
  // xs mapping: image row R -> xs row R-(ti0-2); image col C -> xs col C-(tj0-4)
  for (int idx = tid; idx < U0_R * U0_C; idx += 256) {
    int r = idx >> 6;          // / 64
    int c = idx & 63;
    float gx = 0.5f * (xs[r + 2][c + 4] - xs[r][c + 4]);      // rows (ti0-1+r)±1
    float gy = 0.5f * (xs[r + 1][c + 5] - xs[r + 1][c + 3]);  // cols (tj0+c)±1
    u0s[r][c] = gx * rsqrtf(1.0f + gx * gx + gy * gy);
  }
  // ---- u1 = gy/norm on (32 x 66): rows ti0..ti0+TH-1, cols tj0-1..tj0+TW --
  for (int idx = tid; idx < U1_R * U1_C; idx += 256) {
    int r = idx / U1_C;
    int c = idx - r * U1_C;
    float gx = 0.5f * (xs[r + 3][c + 3] - xs[r + 1][c + 3]);  // rows (ti0+r)±1
    float gy = 0.5f * (xs[r + 2][c + 4] - xs[r + 2][c + 2]);  // cols (tj0-1+c)±1
    u1s[r][c] = gy * rsqrtf(1.0f + gx * gx + gy * gy);
  }
  __syncthreads();

  // ---- u ghost fixups at image boundaries (extrapolate u, not u(ghost x)) -
  if (ti0 == 0 && tid < U0_C)                      // image row -1
    u0s[0][tid] = 2.0f * u0s[1][tid] - u0s[2][tid];
  if (ti0 + TH == H && tid < U0_C)                 // image row H
    u0s[U0_R - 1][tid] = 2.0f * u0s[U0_R - 2][tid] - u0s[U0_R - 3][tid];
  if (tj0 == 0 && tid < U1_R)                      // image col -1
    u1s[tid][0] = 2.0f * u1s[tid][1] - u1s[tid][2];
  if (tj0 + TW == W && tid < U1_R)                 // image col W
    u1s[tid][U1_C - 1] = 2.0f * u1s[tid][U1_C - 2] - u1s[tid][U1_C - 3];
  __syncthreads();

  // ---- divergence + store (float4 per thread, 2 rows x 4 cols each) -------
  const int lq = tid & 15;       // col quad: cols 4*lq .. 4*lq+3
  const int r0 = tid >> 4;       // 0..15
#pragma unroll
  for (int half = 0; half < 2; ++half) {
    const int i  = r0 + 16 * half;   // local row 0..31
    const int c0 = 4 * lq;
    float o[4];
#pragma unroll
    for (int k = 0; k < 4; ++k) {
      const int c = c0 + k;
      // u0s row i   <-> image row (ti0+i)-1 ; row i+2 <-> +1
      float dh = 0.5f * (u0s[i + 2][c] - u0s[i][c]);
      // u1s col c   <-> image col (tj0+c)-1 ; col c+2 <-> +1
      float dw = 0.5f * (u1s[i][c + 2] - u1s[i][c]);
      o[k] = dh + dw;
    }
    *reinterpret_cast<float4*>(Ds + (size_t)(ti0 + i) * W + (tj0 + c0)) =
        make_float4(o[0], o[1], o[2], o[3]);
  }
}

extern "C" void kernel_launch(void* const* d_in, const int* in_sizes, int n_in,
                              void* d_out, int out_size, void* d_ws, size_t ws_size,
                              hipStream_t stream) {
  const float* X = (const float*)d_in[0];
  float* Dout = (float*)d_out;
  const int n_slices = in_sizes[0] / (H * W);   // 8*4 = 32
  dim3 grid(W / TW, H / TH, n_slices);          // (16, 32, 32) = 16384 blocks
  tv_grad_kernel<<<grid, dim3(256, 1, 1), 0, stream>>>(X, Dout);
}

// Round 3
// 240.541 us; speedup vs baseline: 1.2654x; 1.2654x over previous
//
#include <hip/hip_runtime.h>

// TV-gradient divergence, register row-walk version (no LDS, no barriers).
// d = ddH(u0) + ddW(u1), u = grad(x)/sqrt(1+|grad(x)|^2), jnp.gradient semantics.
// One-sided boundary diffs == central diffs against linearly-extrapolated ghosts:
// ghost x rows/cols for the inner gradient, ghost u0 rows / u1 cols for the outer.
//
// Each wave: 64 lanes x float4 = 256-col strip, walks NR output rows with rolling
// registers. u0 and u1 share one rsqrt per grid point. Column neighbors via
// __shfl; strip-boundary u1 (cols c0-1, c0+256) maintained as uniform scalars
// from uniform float2 edge loads (L2 hits - neighbor strip's data).

constexpr int H = 1024, W = 1024;
constexpr int NR = 32;            // output rows per wave
constexpr int NCH = H / NR;       // 32 row chunks
// 4 col strips of 256; block = 4 waves = 4 strips of one (slice,chunk)

__device__ __forceinline__ float4 ld4(const float* p) { return *reinterpret_cast<const float4*>(p); }
__device__ __forceinline__ float2 ld2(const float* p) { return *reinterpret_cast<const float2*>(p); }
__device__ __forceinline__ float4 f4_ghost(const float4 a, const float4 b) {  // 2a-b
  return make_float4(2.f*a.x-b.x, 2.f*a.y-b.y, 2.f*a.z-b.z, 2.f*a.w-b.w);
}

struct U4 { float4 u0, u1; };

// u at row r from x rows (r-1, r, r+1) = (xm, x0, xp). eL/eR: x(r, c0-1 / c0+256).
__device__ __forceinline__ U4 compute_u(const float4 xm, const float4 x0, const float4 xp,
                                        float eL, float eR, bool LE, bool RE,
                                        bool is0, bool is63) {
  float xl = __shfl_up(x0.w, 1);
  if (is0)  xl = LE ? (2.0f * x0.x - x0.y) : eL;
  float xr = __shfl_down(x0.x, 1);
  if (is63) xr = RE ? (2.0f * x0.w - x0.z) : eR;
  float gx[4] = { xp.x - xm.x, xp.y - xm.y, xp.z - xm.z, xp.w - xm.w };
  float gy[4] = { x0.y - xl,   x0.z - x0.x, x0.w - x0.y, xr - x0.z   };
  U4 o;
  float* u0 = &o.u0.x; float* u1 = &o.u1.x;
#pragma unroll
  for (int k = 0; k < 4; ++k) {
    float t  = fmaf(gx[k], gx[k], gy[k] * gy[k]);
    float hr = 0.5f * rsqrtf(fmaf(0.25f, t, 1.0f));   // 0.5/norm (gx,gy are 2x true grad)
    u0[k] = gx[k] * hr;
    u1[k] = gy[k] * hr;
  }
  return o;
}

__device__ __forceinline__ float edge_u1(float gx, float gy) {
  float t = fmaf(gx, gx, gy * gy);
  return 0.5f * gy * rsqrtf(fmaf(0.25f, t, 1.0f));
}

__global__ __launch_bounds__(256) void tv_grad_kernel(const float* __restrict__ X,
                                                      float* __restrict__ D) {
  const int tid  = threadIdx.x;
  const int lane = tid & 63;
  const int gw   = blockIdx.x * 4 + (tid >> 6);
  const int slice = gw >> 7;          // 128 waves per slice (32 chunks x 4 strips)
  const int rem   = gw & 127;
  const int r0    = (rem >> 2) * NR;
  const int c0    = (rem & 3) << 8;
  const int j0    = c0 + (lane << 2);
  const bool is0 = (lane == 0), is63 = (lane == 63);
  const bool LE = (c0 == 0), RE = (c0 + 256 == W);
  const float* Xs = X + (size_t)slice * H * W;
  float*       Ds = D + (size_t)slice * H * W;
  const int cl = LE ? 0 : (c0 - 2);       // float2 covers cols (c0-2, c0-1); clamped junk if LE
  const int cr = RE ? (W - 2) : (c0 + 256); // float2 covers (c0+256, c0+257); clamped junk if RE

  // ---------------- prologue: rows r0-2 .. r0+2 ----------------------------
  const float* pA = Xs + (size_t)max(r0 - 2, 0) * W;
  const float* pB = Xs + (size_t)max(r0 - 1, 0) * W;
  const float* p0 = Xs + (size_t)r0 * W;
  const float* p1 = Xs + (size_t)(r0 + 1) * W;
  const float* p2 = Xs + (size_t)(r0 + 2) * W;
  float4 xP2 = ld4(pA + j0), xP1 = ld4(pB + j0), x00 = ld4(p0 + j0);
  float4 xB  = ld4(p1 + j0), xN  = ld4(p2 + j0);
  float2 LP1 = ld2(pB + cl), L00 = ld2(p0 + cl), L01 = ld2(p1 + cl), L02 = ld2(p2 + cl);
  float2 RP1 = ld2(pB + cr), R00 = ld2(p0 + cr), R01 = ld2(p1 + cr), R02 = ld2(p2 + cr);
  if (r0 == 0) {                      // ghost row -1 = 2*x(0) - x(1)
    xP1 = f4_ghost(x00, xB);
    LP1 = make_float2(2.f*L00.x - L01.x, 2.f*L00.y - L01.y);
    RP1 = make_float2(2.f*R00.x - R01.x, 2.f*R00.y - R01.y);
    // xP2 stays row-0 data: u0m below is garbage but overwritten at i==0.
  }
  // u0(r0-1) (garbage if r0==0; fixed in first iteration)
  float4 u0m = compute_u(xP2, xP1, x00, LP1.y, RP1.x, LE, RE, is0, is63).u0;
  // u(r0)
  U4 uc = compute_u(xP1, x00, xB, L00.y, R00.x, LE, RE, is0, is63);
  float4 u00 = uc.u0, u1c = uc.u1;
  // uniform strip-edge u1 at row r0: cols c0-1 and c0+256
  float u1Lc, u1Rc;
  {
    float xq0   = __shfl(x00.x, 0);
    float xq255 = __shfl(x00.w, 63);
    u1Lc = edge_u1(L01.y - LP1.y, xq0 - L00.x);
    u1Rc = edge_u1(R01.x - RP1.x, R00.y - xq255);
  }
  // rolling state
  float4 xA = x00;                                    // x(i)
  float lA = L00.y, lB1 = L01.y, lB2 = L01.x;         // x(i,c0-1), x(i+1,c0-1), x(i+1,c0-2)
  float lN1 = L02.y, lN2 = L02.x;                     // raw row i+2
  float rA = R00.x, rB1 = R01.x, rB2 = R01.y;
  float rN1 = R02.x, rN2 = R02.y;

  // ---------------- main walk ----------------------------------------------
#pragma unroll 4
  for (int i = r0; i < r0 + NR; ++i) {
    // prefetch row i+3 (consumed next iteration)
    const float* pf = Xs + (size_t)min(i + 3, H - 1) * W;
    float4 xF = ld4(pf + j0);
    float2 LF = ld2(pf + cl);
    float2 RF = ld2(pf + cr);

    // materialize row i+2 (ghost beyond bottom edge)
    const bool gb = (i + 2 >= H);
    float4 xC; float lC1, rC1;
    if (gb) { xC = f4_ghost(xB, xA); lC1 = 2.f*lB1 - lA; rC1 = 2.f*rB1 - rA; }
    else    { xC = xN;               lC1 = lN1;          rC1 = rN1; }
    const float lC2 = lN2, rC2 = rN2;   // unused at bottom ghost rows

    // u(i+1)
    float4 u0p, u1p; float u1Lp, u1Rp;
    if (i < H - 1) {
      U4 up = compute_u(xA, xB, xC, lB1, rB1, LE, RE, is0, is63);
      u0p = up.u0; u1p = up.u1;
      float xb0   = __shfl(xB.x, 0);    // x(i+1, c0)
      float xb255 = __shfl(xB.w, 63);   // x(i+1, c0+255)
      u1Lp = edge_u1(lC1 - lA, xb0 - lB2);
      u1Rp = edge_u1(rC1 - rA, rB2 - xb255);
    } else {                            // i == H-1: ghost u0(H) = 2 u0(H-1) - u0(H-2)
      u0p = f4_ghost(u00, u0m);
      u1p = u1c; u1Lp = u1Lc; u1Rp = u1Rc;
    }
    if (i == 0) u0m = f4_ghost(u00, u0p);   // ghost u0(-1) = 2 u0(0) - u0(1)

    // d(i) = 0.5*(u0(i+1)-u0(i-1)) + 0.5*(u1(i,j+1)-u1(i,j-1))
    float u1l = __shfl_up(u1c.w, 1);
    if (is0)  u1l = LE ? (2.f*u1c.x - u1c.y) : u1Lc;
    float u1r = __shfl_down(u1c.x, 1);
    if (is63) u1r = RE ? (2.f*u1c.w - u1c.z) : u1Rc;
    float4 d;
    d.x = 0.5f * ((u0p.x - u0m.x) + (u1c.y - u1l));
    d.y = 0.5f * ((u0p.y - u0m.y) + (u1c.z - u1c.x));
    d.z = 0.5f * ((u0p.z - u0m.z) + (u1c.w - u1c.y));
    d.w = 0.5f * ((u0p.w - u0m.w) + (u1r  - u1c.z));
    *reinterpret_cast<float4*>(Ds + (size_t)i * W + j0) = d;

    // roll
    u0m = u00; u00 = u0p; u1c = u1p; u1Lc = u1Lp; u1Rc = u1Rp;
    xA = xB; xB = xC; xN = xF;
    lA = lB1; lB1 = lC1; lB2 = lC2; lN1 = LF.y; lN2 = LF.x;
    rA = rB1; rB1 = rC1; rB2 = rC2; rN1 = RF.x; rN2 = RF.y;
  }
}

extern "C" void kernel_launch(void* const* d_in, const int* in_sizes, int n_in,
                              void* d_out, int out_size, void* d_ws, size_t ws_size,
                              hipStream_t stream) {
  const float* X = (const float*)d_in[0];
  float* Dout = (float*)d_out;
  const int n_slices = in_sizes[0] / (H * W);          // 32
  dim3 grid(n_slices * NCH, 1, 1);                     // 1024 blocks x 4 waves
  tv_grad_kernel<<<grid, dim3(256, 1, 1), 0, stream>>>(X, Dout);
}